// Round 15
// baseline (177.085 us; speedup 1.0000x reference)
//
#include <hip/hip_runtime.h>
#include <hip/hip_bf16.h>

#define B_   4
#define S_   4096
#define D_   1024
#define M_   (B_ * S_)   // 16384
#define K_   1024
#define BK   64
#define NT   (K_ / BK)   // 16

typedef __attribute__((ext_vector_type(4))) float f32x4;
typedef __attribute__((ext_vector_type(8))) short bf16x8;
typedef unsigned short ushort_t;
typedef unsigned int uint_t;

#define SCHEDB __builtin_amdgcn_sched_barrier(0)
#define MFMA16(a, b, c) __builtin_amdgcn_mfma_f32_16x16x32_bf16(a, b, c, 0, 0, 0)

__device__ inline ushort_t f2bf(float f) {
    union { float f; unsigned u; } v; v.f = f;
    unsigned r = v.u + 0x7fffu + ((v.u >> 16) & 1u);
    return (ushort_t)(r >> 16);
}
__device__ inline float bf2f(ushort_t s) {
    union { unsigned u; float f; } v; v.u = ((unsigned)s) << 16; return v.f;
}

// ---------------- fused preprocessing: convert x + transpose W_in + transpose W_out ----------------
__global__ __launch_bounds__(256) void prep_kernel(
    const float4* __restrict__ x, ushort_t* __restrict__ xb,
    const float* __restrict__ W_in, const float* __restrict__ W_out,
    ushort_t* __restrict__ winT, ushort_t* __restrict__ woT)
{
    const int bid = blockIdx.x, tid = threadIdx.x;
    if (bid < 8192) {
        int i = bid * 256 + tid;
        float4 a = x[2 * i], b = x[2 * i + 1];
        union { ushort_t s[8]; uint4 v; } u;
        u.s[0] = f2bf(a.x); u.s[1] = f2bf(a.y); u.s[2] = f2bf(a.z); u.s[3] = f2bf(a.w);
        u.s[4] = f2bf(b.x); u.s[5] = f2bf(b.y); u.s[6] = f2bf(b.z); u.s[7] = f2bf(b.w);
        ((uint4*)xb)[i] = u.v;
        return;
    }
    __shared__ float tile[32][33];
    const int tx = tid & 31, ty = tid >> 5;   // 32 x 8, 4 rows per thread
    if (bid < 10240) {
        int wb = bid - 8192;
        int n0 = (wb & 63) * 32, k0 = (wb >> 6) * 32;
        int ci = (n0 >> 1) + (tx & 15) + ((tx & 16) ? 1024 : 0);
#pragma unroll
        for (int j = 0; j < 4; ++j)
            tile[ty + 8 * j][tx] = W_in[(long)(k0 + ty + 8 * j) * 2048 + ci];
        __syncthreads();
#pragma unroll
        for (int j = 0; j < 4; ++j)
            winT[(long)(n0 + ty + 8 * j) * 1024 + k0 + tx] = f2bf(tile[tx][ty + 8 * j]);
    } else {
        int wb = bid - 10240;
        int n0 = (wb & 31) * 32, k0 = (wb >> 5) * 32;
#pragma unroll
        for (int j = 0; j < 4; ++j)
            tile[ty + 8 * j][tx] = W_out[(long)(k0 + ty + 8 * j) * 1024 + n0 + tx];
        __syncthreads();
#pragma unroll
        for (int j = 0; j < 4; ++j)
            woT[(long)(n0 + ty + 8 * j) * 1024 + k0 + tx] = f2bf(tile[tx][ty + 8 * j]);
    }
}

// ---------------- stage one 128x64 bf16 half-tile (16KB) via global_load_lds ----------------
// LDS dest linear [128 rows][128B]; global source pre-swizzled: slot' = slot ^ (row&7)
__device__ inline void stage_half(const char* gtile, char* ldst, int soff0, int soff1, int w) {
    __builtin_amdgcn_global_load_lds((const __attribute__((address_space(1))) void*)(gtile + soff0),
                                     (__attribute__((address_space(3))) void*)(ldst + w * 2048), 16, 0, 0);
    __builtin_amdgcn_global_load_lds((const __attribute__((address_space(1))) void*)(gtile + soff1),
                                     (__attribute__((address_space(3))) void*)(ldst + w * 2048 + 1024), 16, 0, 0);
}

// ---------------- 256x256 GEMM, BK=64, 8 waves, one-phase-ahead reads, counted lgkm/vmcnt ----------------
// GATE=0 additionally fuses the EMA scan: computes h rows [m0, m0+256) from gsrc into hdst (=A)
// before staging A. Sibling blocks (same m0, different n0) write byte-identical h values.
template<int NBN, int GATE>
__global__ __launch_bounds__(512, 1) void gemm8_kernel(
    const ushort_t* __restrict__ A, const ushort_t* __restrict__ Bm,
    const float* __restrict__ bias, void* __restrict__ outp,
    const ushort_t* __restrict__ gsrc, ushort_t* __restrict__ hdst)
{
    extern __shared__ char smem[];
    const int tid = threadIdx.x;
    const int l = tid & 63, w = tid >> 6;
    const int wm = w >> 2, wn = w & 3;
    const int lrow = l & 15, kgrp = l >> 4;

    const int nwg = gridDim.x, cpx = nwg >> 3, bid = blockIdx.x;
    const int wg = (bid & 7) * cpx + (bid >> 3);
    const long m0 = (long)(wg / NBN) * 256;
    const long n0 = (long)(wg % NBN) * 256;

    const char* gA = (const char*)A + m0 * 2048;
    const char* gB = (const char*)Bm + n0 * 2048;

    const int lsw = (((l & 7) ^ (l >> 3)) << 4);
    const int soff0 = ((w * 2 + 0) * 8 + (l >> 3)) * 2048 + lsw;
    const int soff1 = ((w * 2 + 1) * 8 + (l >> 3)) * 2048 + lsw;

    const int arow = (wm * 128 + lrow) * 128;
    const int brow = (wn * 64 + lrow) * 128;
    const int sw0 = ((kgrp ^ (l & 7)) << 4);
    const int sw1 = (((4 + kgrp) ^ (l & 7)) << 4);

    f32x4 acc[8][4];
#pragma unroll
    for (int i = 0; i < 8; ++i)
#pragma unroll
        for (int j = 0; j < 4; ++j) acc[i][j] = f32x4{0.f, 0.f, 0.f, 0.f};

    bf16x8 af[4][2], bf[2][2], af2[4][2], bf2[2][2];

    char* s1 = smem + 65536;
    if (GATE) {
        // prologue: stage tiles 0 and 1 fully; wait tile 0
        stage_half(gA,              smem,          soff0, soff1, w);  // A0(0)
        stage_half(gA + 262144,     smem + 16384,  soff0, soff1, w);  // A1(0)
        stage_half(gB,              smem + 32768,  soff0, soff1, w);  // B0(0)
        stage_half(gB + 262144,     smem + 49152,  soff0, soff1, w);  // B1(0)
        stage_half(gA + 128,        s1,            soff0, soff1, w);  // A0(1)
        stage_half(gA + 262144 + 128, s1 + 16384,  soff0, soff1, w);  // A1(1)
        stage_half(gB + 128,        s1 + 32768,    soff0, soff1, w);  // B0(1)
        stage_half(gB + 262144 + 128, s1 + 49152,  soff0, soff1, w);  // B1(1)
        asm volatile("s_waitcnt vmcnt(8)" ::: "memory");
    } else {
        // stage B tiles 0,1 first (h-independent; latency hides under scan)
        stage_half(gB,              smem + 32768,  soff0, soff1, w);
        stage_half(gB + 262144,     smem + 49152,  soff0, soff1, w);
        stage_half(gB + 128,        s1 + 32768,    soff0, soff1, w);
        stage_half(gB + 262144 + 128, s1 + 49152,  soff0, soff1, w);
        // fused EMA scan: h rows [m0, m0+256), 2 channels/thread, halo 64
        {
            const int d = tid * 2;
            const int s0 = (int)(m0 & 4095);
            const int halo = s0 < 64 ? s0 : 64;
            const ushort_t* gp = gsrc + (m0 - halo) * 1024 + d;
            ushort_t* hp = hdst + m0 * 1024 + d;
            float e0 = 0.f, e1 = 0.f;
            for (int t = 0; t < halo; ++t, gp += 1024) {
                uint_t v = *(const uint_t*)gp;
                e0 = 0.9f * e0 + 0.1f * bf2f((ushort_t)(v & 0xffffu));
                e1 = 0.9f * e1 + 0.1f * bf2f((ushort_t)(v >> 16));
            }
#pragma unroll 4
            for (int t = 0; t < 256; ++t, gp += 1024, hp += 1024) {
                uint_t v = *(const uint_t*)gp;
                e0 = 0.9f * e0 + 0.1f * bf2f((ushort_t)(v & 0xffffu));
                e1 = 0.9f * e1 + 0.1f * bf2f((ushort_t)(v >> 16));
                *(uint_t*)hp = (((uint_t)f2bf(e1)) << 16) | (uint_t)f2bf(e0);
            }
        }
        asm volatile("s_waitcnt vmcnt(0)" ::: "memory");   // h stores + B stages complete
        __syncthreads();
        // stage A tiles 0,1 from freshly-written h
        stage_half(gA,              smem,          soff0, soff1, w);
        stage_half(gA + 262144,     smem + 16384,  soff0, soff1, w);
        stage_half(gA + 128,        s1,            soff0, soff1, w);
        stage_half(gA + 262144 + 128, s1 + 16384,  soff0, soff1, w);
        asm volatile("s_waitcnt vmcnt(4)" ::: "memory");   // tile-0 A landed; tile-1 A in flight
    }
    __builtin_amdgcn_s_barrier();
#pragma unroll
    for (int fm = 0; fm < 4; ++fm) {
        af[fm][0] = *(const bf16x8*)(smem + arow + fm * 2048 + sw0);
        af[fm][1] = *(const bf16x8*)(smem + arow + fm * 2048 + sw1);
    }
#pragma unroll
    for (int fn = 0; fn < 2; ++fn) {
        bf[fn][0] = *(const bf16x8*)(smem + 32768 + brow + fn * 2048 + sw0);
        bf[fn][1] = *(const bf16x8*)(smem + 32768 + brow + fn * 2048 + sw1);
    }
    SCHEDB;

    for (int t = 0; t < NT; ++t) {
        char* cur = smem + ((t & 1) << 16);
        char* nxt = smem + (((t + 1) & 1) << 16);

        // ---- ph0: read bf2(t); vmcnt(4); lgkm(4); MFMA Q00 ----
#pragma unroll
        for (int fn = 0; fn < 2; ++fn) {
            bf2[fn][0] = *(const bf16x8*)(cur + 32768 + brow + (fn + 2) * 2048 + sw0);
            bf2[fn][1] = *(const bf16x8*)(cur + 32768 + brow + (fn + 2) * 2048 + sw1);
        }
        SCHEDB;
        asm volatile("s_waitcnt vmcnt(4)" ::: "memory");
        asm volatile("s_waitcnt lgkmcnt(4)" ::: "memory");
        SCHEDB;
        __builtin_amdgcn_s_setprio(1);
#pragma unroll
        for (int fm = 0; fm < 4; ++fm)
#pragma unroll
            for (int fn = 0; fn < 2; ++fn) {
                acc[fm][fn] = MFMA16(af[fm][0], bf[fn][0], acc[fm][fn]);
                acc[fm][fn] = MFMA16(af[fm][1], bf[fn][1], acc[fm][fn]);
            }
        __builtin_amdgcn_s_setprio(0);
        SCHEDB;
        __builtin_amdgcn_s_barrier();

        // ---- ph1: read af2(t); stage A0(t+2); lgkm(8); MFMA Q01 ----
#pragma unroll
        for (int fm = 0; fm < 4; ++fm) {
            af2[fm][0] = *(const bf16x8*)(cur + arow + (fm + 4) * 2048 + sw0);
            af2[fm][1] = *(const bf16x8*)(cur + arow + (fm + 4) * 2048 + sw1);
        }
        if (t + 2 < NT) stage_half(gA + (t + 2) * 128, cur, soff0, soff1, w);
        SCHEDB;
        asm volatile("s_waitcnt lgkmcnt(8)" ::: "memory");
        SCHEDB;
        __builtin_amdgcn_s_setprio(1);
#pragma unroll
        for (int fm = 0; fm < 4; ++fm)
#pragma unroll
            for (int fn = 0; fn < 2; ++fn) {
                acc[fm][fn + 2] = MFMA16(af[fm][0], bf2[fn][0], acc[fm][fn + 2]);
                acc[fm][fn + 2] = MFMA16(af[fm][1], bf2[fn][1], acc[fm][fn + 2]);
            }
        __builtin_amdgcn_s_setprio(0);
        SCHEDB;
        __builtin_amdgcn_s_barrier();

        // ---- ph2: stage B0(t+2); vmcnt(4|0); lgkm(0); MFMA Q10 ----
        if (t + 2 < NT) stage_half(gB + (t + 2) * 128, cur + 32768, soff0, soff1, w);
        SCHEDB;
        if (t < NT - 2) asm volatile("s_waitcnt vmcnt(4)" ::: "memory");
        else            asm volatile("s_waitcnt vmcnt(0)" ::: "memory");
        asm volatile("s_waitcnt lgkmcnt(0)" ::: "memory");
        SCHEDB;
        __builtin_amdgcn_s_setprio(1);
#pragma unroll
        for (int fm = 0; fm < 4; ++fm)
#pragma unroll
            for (int fn = 0; fn < 2; ++fn) {
                acc[fm + 4][fn] = MFMA16(af2[fm][0], bf[fn][0], acc[fm + 4][fn]);
                acc[fm + 4][fn] = MFMA16(af2[fm][1], bf[fn][1], acc[fm + 4][fn]);
            }
        __builtin_amdgcn_s_setprio(0);
        SCHEDB;
        __builtin_amdgcn_s_barrier();

        // ---- ph3: read af,bf(t+1); stage B1(t+2), A1(t+2); MFMA Q11 ----
        if (t + 1 < NT) {
#pragma unroll
            for (int fm = 0; fm < 4; ++fm) {
                af[fm][0] = *(const bf16x8*)(nxt + arow + fm * 2048 + sw0);
                af[fm][1] = *(const bf16x8*)(nxt + arow + fm * 2048 + sw1);
            }
#pragma unroll
            for (int fn = 0; fn < 2; ++fn) {
                bf[fn][0] = *(const bf16x8*)(nxt + 32768 + brow + fn * 2048 + sw0);
                bf[fn][1] = *(const bf16x8*)(nxt + 32768 + brow + fn * 2048 + sw1);
            }
        }
        if (t + 2 < NT) {
            stage_half(gB + 262144 + (t + 2) * 128, cur + 49152, soff0, soff1, w);
            stage_half(gA + 262144 + (t + 2) * 128, cur + 16384, soff0, soff1, w);
        }
        SCHEDB;
        __builtin_amdgcn_s_setprio(1);
#pragma unroll
        for (int fm = 0; fm < 4; ++fm)
#pragma unroll
            for (int fn = 0; fn < 2; ++fn) {
                acc[fm + 4][fn + 2] = MFMA16(af2[fm][0], bf2[fn][0], acc[fm + 4][fn + 2]);
                acc[fm + 4][fn + 2] = MFMA16(af2[fm][1], bf2[fn][1], acc[fm + 4][fn + 2]);
            }
        __builtin_amdgcn_s_setprio(0);
        SCHEDB;
        __builtin_amdgcn_s_barrier();
    }

    // ---------------- epilogue ----------------
    const long row0 = m0 + wm * 128 + kgrp * 4;
    if (GATE) {
        ushort_t* g = (ushort_t*)outp;
#pragma unroll
        for (int fm = 0; fm < 8; ++fm) {
#pragma unroll
            for (int fp = 0; fp < 2; ++fp) {
                int c = (int)(n0 >> 1) + wn * 32 + fp * 16 + lrow;
                float bg = bias[c], bh = bias[1024 + c];
#pragma unroll
                for (int r = 0; r < 4; ++r) {
                    long rr = row0 + fm * 16 + r;
                    float gate = acc[fm][fp * 2][r] + bg;
                    float hid  = acc[fm][fp * 2 + 1][r] + bh;
                    float sg = 1.0f / (1.0f + expf(-gate));
                    float sh = 1.0f / (1.0f + expf(-hid));
                    g[rr * 1024 + c] = f2bf(sg * hid * sh);
                }
            }
        }
    } else {
        float* o = (float*)outp;
#pragma unroll
        for (int fm = 0; fm < 8; ++fm)
#pragma unroll
            for (int fn = 0; fn < 4; ++fn) {
                int c = (int)n0 + wn * 64 + fn * 16 + lrow;
                float bo = bias[c];
#pragma unroll
                for (int r = 0; r < 4; ++r) {
                    long rr = row0 + fm * 16 + r;
                    o[rr * 1024 + c] = acc[fm][fn][r] + bo;
                }
            }
    }
}

extern "C" void kernel_launch(void* const* d_in, const int* in_sizes, int n_in,
                              void* d_out, int out_size, void* d_ws, size_t ws_size,
                              hipStream_t stream) {
    const float* x     = (const float*)d_in[0];
    const float* W_in  = (const float*)d_in[1];
    const float* b_in  = (const float*)d_in[2];
    const float* W_out = (const float*)d_in[3];
    const float* b_out = (const float*)d_in[4];
    float* outp = (float*)d_out;

    char* ws = (char*)d_ws;
    ushort_t* xb   = (ushort_t*)ws;                        // 32 MB: x bf16, later reused for h bf16
    ushort_t* winT = (ushort_t*)(ws + 33554432);           // 4 MB
    ushort_t* woT  = (ushort_t*)(ws + 33554432 + 4194304); // 2 MB
    ushort_t* gbuf = (ushort_t*)(ws + 33554432 + 6291456); // 32 MB

    hipFuncSetAttribute((const void*)&gemm8_kernel<8, 1>, hipFuncAttributeMaxDynamicSharedMemorySize, 131072);
    hipFuncSetAttribute((const void*)&gemm8_kernel<4, 0>, hipFuncAttributeMaxDynamicSharedMemorySize, 131072);

    prep_kernel<<<11264, 256, 0, stream>>>((const float4*)x, xb, W_in, W_out, winT, woT);
    gemm8_kernel<8, 1><<<512, 512, 131072, stream>>>(xb, winT, b_in, (void*)gbuf, nullptr, nullptr);
    gemm8_kernel<4, 0><<<256, 512, 131072, stream>>>(xb, woT, b_out, (void*)outp, gbuf, xb);
}

// Round 16
// 166.717 us; speedup vs baseline: 1.0622x; 1.0622x over previous
//
#include <hip/hip_runtime.h>
#include <hip/hip_bf16.h>

#define B_   4
#define S_   4096
#define D_   1024
#define M_   (B_ * S_)   // 16384
#define K_   1024
#define BK   64
#define NT   (K_ / BK)   // 16

typedef __attribute__((ext_vector_type(4))) float f32x4;
typedef __attribute__((ext_vector_type(8))) short bf16x8;
typedef unsigned short ushort_t;
typedef unsigned int uint_t;

#define SCHEDB __builtin_amdgcn_sched_barrier(0)
#define MFMA16(a, b, c) __builtin_amdgcn_mfma_f32_16x16x32_bf16(a, b, c, 0, 0, 0)

__device__ inline ushort_t f2bf(float f) {
    union { float f; unsigned u; } v; v.f = f;
    unsigned r = v.u + 0x7fffu + ((v.u >> 16) & 1u);
    return (ushort_t)(r >> 16);
}
__device__ inline float bf2f(ushort_t s) {
    union { unsigned u; float f; } v; v.u = ((unsigned)s) << 16; return v.f;
}

// ---------------- fused preprocessing: convert x + transpose W_in + transpose W_out ----------------
// blocks [0,8192): convert x fp32 -> bf16 (8 elems/thread)
// blocks [8192,10240): W_in [1024][2048] -> WinT [2048][1024] bf16, gate/hidden interleaved by 16 cols
// blocks [10240,11264): W_out [1024][1024] -> WoT [1024][1024] bf16
__global__ __launch_bounds__(256) void prep_kernel(
    const float4* __restrict__ x, ushort_t* __restrict__ xb,
    const float* __restrict__ W_in, const float* __restrict__ W_out,
    ushort_t* __restrict__ winT, ushort_t* __restrict__ woT)
{
    const int bid = blockIdx.x, tid = threadIdx.x;
    if (bid < 8192) {
        int i = bid * 256 + tid;
        float4 a = x[2 * i], b = x[2 * i + 1];
        union { ushort_t s[8]; uint4 v; } u;
        u.s[0] = f2bf(a.x); u.s[1] = f2bf(a.y); u.s[2] = f2bf(a.z); u.s[3] = f2bf(a.w);
        u.s[4] = f2bf(b.x); u.s[5] = f2bf(b.y); u.s[6] = f2bf(b.z); u.s[7] = f2bf(b.w);
        ((uint4*)xb)[i] = u.v;
        return;
    }
    __shared__ float tile[32][33];
    const int tx = tid & 31, ty = tid >> 5;   // 32 x 8, 4 rows per thread
    if (bid < 10240) {
        int wb = bid - 8192;
        int n0 = (wb & 63) * 32, k0 = (wb >> 6) * 32;
        int ci = (n0 >> 1) + (tx & 15) + ((tx & 16) ? 1024 : 0);
#pragma unroll
        for (int j = 0; j < 4; ++j)
            tile[ty + 8 * j][tx] = W_in[(long)(k0 + ty + 8 * j) * 2048 + ci];
        __syncthreads();
#pragma unroll
        for (int j = 0; j < 4; ++j)
            winT[(long)(n0 + ty + 8 * j) * 1024 + k0 + tx] = f2bf(tile[tx][ty + 8 * j]);
    } else {
        int wb = bid - 10240;
        int n0 = (wb & 31) * 32, k0 = (wb >> 5) * 32;
#pragma unroll
        for (int j = 0; j < 4; ++j)
            tile[ty + 8 * j][tx] = W_out[(long)(k0 + ty + 8 * j) * 1024 + n0 + tx];
        __syncthreads();
#pragma unroll
        for (int j = 0; j < 4; ++j)
            woT[(long)(n0 + ty + 8 * j) * 1024 + k0 + tx] = f2bf(tile[tx][ty + 8 * j]);
    }
}

// ---------------- stage one 128x64 bf16 half-tile (16KB) via global_load_lds ----------------
// LDS dest linear [128 rows][128B]; global source pre-swizzled: slot' = slot ^ (row&7)
__device__ inline void stage_half(const char* gtile, char* ldst, int soff0, int soff1, int w) {
    __builtin_amdgcn_global_load_lds((const __attribute__((address_space(1))) void*)(gtile + soff0),
                                     (__attribute__((address_space(3))) void*)(ldst + w * 2048), 16, 0, 0);
    __builtin_amdgcn_global_load_lds((const __attribute__((address_space(1))) void*)(gtile + soff1),
                                     (__attribute__((address_space(3))) void*)(ldst + w * 2048 + 1024), 16, 0, 0);
}

// ---------------- 256x256 GEMM, BK=64, 8 waves, one-phase-ahead reads, counted lgkm/vmcnt ----------------
template<int NBN, int GATE>
__global__ __launch_bounds__(512, 1) void gemm8_kernel(
    const ushort_t* __restrict__ A, const ushort_t* __restrict__ Bm,
    const float* __restrict__ bias, void* __restrict__ outp)
{
    extern __shared__ char smem[];
    const int tid = threadIdx.x;
    const int l = tid & 63, w = tid >> 6;
    const int wm = w >> 2, wn = w & 3;
    const int lrow = l & 15, kgrp = l >> 4;

    const int nwg = gridDim.x, cpx = nwg >> 3, bid = blockIdx.x;
    const int wg = (bid & 7) * cpx + (bid >> 3);
    const long m0 = (long)(wg / NBN) * 256;
    const long n0 = (long)(wg % NBN) * 256;

    const char* gA = (const char*)A + m0 * 2048;
    const char* gB = (const char*)Bm + n0 * 2048;

    const int lsw = (((l & 7) ^ (l >> 3)) << 4);
    const int soff0 = ((w * 2 + 0) * 8 + (l >> 3)) * 2048 + lsw;
    const int soff1 = ((w * 2 + 1) * 8 + (l >> 3)) * 2048 + lsw;

    const int arow = (wm * 128 + lrow) * 128;
    const int brow = (wn * 64 + lrow) * 128;
    const int sw0 = ((kgrp ^ (l & 7)) << 4);
    const int sw1 = (((4 + kgrp) ^ (l & 7)) << 4);

    f32x4 acc[8][4];
#pragma unroll
    for (int i = 0; i < 8; ++i)
#pragma unroll
        for (int j = 0; j < 4; ++j) acc[i][j] = f32x4{0.f, 0.f, 0.f, 0.f};

    bf16x8 af[4][2], bf[2][2], af2[4][2], bf2[2][2];

    // prologue: stage tiles 0 and 1 fully; wait tile 0; prime Q00(0) frags
    char* s1 = smem + 65536;
    stage_half(gA,              smem,          soff0, soff1, w);  // A0(0)
    stage_half(gA + 262144,     smem + 16384,  soff0, soff1, w);  // A1(0)
    stage_half(gB,              smem + 32768,  soff0, soff1, w);  // B0(0)
    stage_half(gB + 262144,     smem + 49152,  soff0, soff1, w);  // B1(0)
    stage_half(gA + 128,        s1,            soff0, soff1, w);  // A0(1)
    stage_half(gA + 262144 + 128, s1 + 16384,  soff0, soff1, w);  // A1(1)
    stage_half(gB + 128,        s1 + 32768,    soff0, soff1, w);  // B0(1)
    stage_half(gB + 262144 + 128, s1 + 49152,  soff0, soff1, w);  // B1(1)
    asm volatile("s_waitcnt vmcnt(8)" ::: "memory");
    __builtin_amdgcn_s_barrier();
#pragma unroll
    for (int fm = 0; fm < 4; ++fm) {
        af[fm][0] = *(const bf16x8*)(smem + arow + fm * 2048 + sw0);
        af[fm][1] = *(const bf16x8*)(smem + arow + fm * 2048 + sw1);
    }
#pragma unroll
    for (int fn = 0; fn < 2; ++fn) {
        bf[fn][0] = *(const bf16x8*)(smem + 32768 + brow + fn * 2048 + sw0);
        bf[fn][1] = *(const bf16x8*)(smem + 32768 + brow + fn * 2048 + sw1);
    }
    SCHEDB;

    for (int t = 0; t < NT; ++t) {
        char* cur = smem + ((t & 1) << 16);
        char* nxt = smem + (((t + 1) & 1) << 16);

        // ---- ph0: read bf2(t); vmcnt(4); lgkm(4); MFMA Q00 ----
#pragma unroll
        for (int fn = 0; fn < 2; ++fn) {
            bf2[fn][0] = *(const bf16x8*)(cur + 32768 + brow + (fn + 2) * 2048 + sw0);
            bf2[fn][1] = *(const bf16x8*)(cur + 32768 + brow + (fn + 2) * 2048 + sw1);
        }
        SCHEDB;
        asm volatile("s_waitcnt vmcnt(4)" ::: "memory");
        asm volatile("s_waitcnt lgkmcnt(4)" ::: "memory");
        SCHEDB;
        __builtin_amdgcn_s_setprio(1);
#pragma unroll
        for (int fm = 0; fm < 4; ++fm)
#pragma unroll
            for (int fn = 0; fn < 2; ++fn) {
                acc[fm][fn] = MFMA16(af[fm][0], bf[fn][0], acc[fm][fn]);
                acc[fm][fn] = MFMA16(af[fm][1], bf[fn][1], acc[fm][fn]);
            }
        __builtin_amdgcn_s_setprio(0);
        SCHEDB;
        __builtin_amdgcn_s_barrier();

        // ---- ph1: read af2(t); stage A0(t+2); lgkm(8); MFMA Q01 ----
#pragma unroll
        for (int fm = 0; fm < 4; ++fm) {
            af2[fm][0] = *(const bf16x8*)(cur + arow + (fm + 4) * 2048 + sw0);
            af2[fm][1] = *(const bf16x8*)(cur + arow + (fm + 4) * 2048 + sw1);
        }
        if (t + 2 < NT) stage_half(gA + (t + 2) * 128, cur, soff0, soff1, w);
        SCHEDB;
        asm volatile("s_waitcnt lgkmcnt(8)" ::: "memory");
        SCHEDB;
        __builtin_amdgcn_s_setprio(1);
#pragma unroll
        for (int fm = 0; fm < 4; ++fm)
#pragma unroll
            for (int fn = 0; fn < 2; ++fn) {
                acc[fm][fn + 2] = MFMA16(af[fm][0], bf2[fn][0], acc[fm][fn + 2]);
                acc[fm][fn + 2] = MFMA16(af[fm][1], bf2[fn][1], acc[fm][fn + 2]);
            }
        __builtin_amdgcn_s_setprio(0);
        SCHEDB;
        __builtin_amdgcn_s_barrier();

        // ---- ph2: stage B0(t+2); vmcnt(6|0); lgkm(0); MFMA Q10 ----
        if (t + 2 < NT) stage_half(gB + (t + 2) * 128, cur + 32768, soff0, soff1, w);
        SCHEDB;
        if (t < NT - 2) asm volatile("s_waitcnt vmcnt(6)" ::: "memory");
        else            asm volatile("s_waitcnt vmcnt(0)" ::: "memory");
        asm volatile("s_waitcnt lgkmcnt(0)" ::: "memory");
        SCHEDB;
        __builtin_amdgcn_s_setprio(1);
#pragma unroll
        for (int fm = 0; fm < 4; ++fm)
#pragma unroll
            for (int fn = 0; fn < 2; ++fn) {
                acc[fm + 4][fn] = MFMA16(af2[fm][0], bf[fn][0], acc[fm + 4][fn]);
                acc[fm + 4][fn] = MFMA16(af2[fm][1], bf[fn][1], acc[fm + 4][fn]);
            }
        __builtin_amdgcn_s_setprio(0);
        SCHEDB;
        __builtin_amdgcn_s_barrier();

        // ---- ph3: read af,bf(t+1); stage B1(t+2), A1(t+2); MFMA Q11 ----
        if (t + 1 < NT) {
#pragma unroll
            for (int fm = 0; fm < 4; ++fm) {
                af[fm][0] = *(const bf16x8*)(nxt + arow + fm * 2048 + sw0);
                af[fm][1] = *(const bf16x8*)(nxt + arow + fm * 2048 + sw1);
            }
#pragma unroll
            for (int fn = 0; fn < 2; ++fn) {
                bf[fn][0] = *(const bf16x8*)(nxt + 32768 + brow + fn * 2048 + sw0);
                bf[fn][1] = *(const bf16x8*)(nxt + 32768 + brow + fn * 2048 + sw1);
            }
        }
        if (t + 2 < NT) {
            stage_half(gB + 262144 + (t + 2) * 128, cur + 49152, soff0, soff1, w);
            stage_half(gA + 262144 + (t + 2) * 128, cur + 16384, soff0, soff1, w);
        }
        SCHEDB;
        __builtin_amdgcn_s_setprio(1);
#pragma unroll
        for (int fm = 0; fm < 4; ++fm)
#pragma unroll
            for (int fn = 0; fn < 2; ++fn) {
                acc[fm + 4][fn + 2] = MFMA16(af2[fm][0], bf2[fn][0], acc[fm + 4][fn + 2]);
                acc[fm + 4][fn + 2] = MFMA16(af2[fm][1], bf2[fn][1], acc[fm + 4][fn + 2]);
            }
        __builtin_amdgcn_s_setprio(0);
        SCHEDB;
        __builtin_amdgcn_s_barrier();
    }

    // ---------------- epilogue ----------------
    const long row0 = m0 + wm * 128 + kgrp * 4;
    if (GATE) {
        ushort_t* g = (ushort_t*)outp;
#pragma unroll
        for (int fm = 0; fm < 8; ++fm) {
#pragma unroll
            for (int fp = 0; fp < 2; ++fp) {
                int c = (int)(n0 >> 1) + wn * 32 + fp * 16 + lrow;
                float bg = bias[c], bh = bias[1024 + c];
#pragma unroll
                for (int r = 0; r < 4; ++r) {
                    long rr = row0 + fm * 16 + r;
                    float gate = acc[fm][fp * 2][r] + bg;
                    float hid  = acc[fm][fp * 2 + 1][r] + bh;
                    float sg = 1.0f / (1.0f + expf(-gate));
                    float sh = 1.0f / (1.0f + expf(-hid));
                    g[rr * 1024 + c] = f2bf(sg * hid * sh);
                }
            }
        }
    } else {
        float* o = (float*)outp;
#pragma unroll
        for (int fm = 0; fm < 8; ++fm)
#pragma unroll
            for (int fn = 0; fn < 4; ++fn) {
                int c = (int)n0 + wn * 64 + fn * 16 + lrow;
                float bo = bias[c];
#pragma unroll
                for (int r = 0; r < 4; ++r) {
                    long rr = row0 + fm * 16 + r;
                    o[rr * 1024 + c] = acc[fm][fn][r] + bo;
                }
            }
    }
}

// ---------------- EMA scan: 256 blocks, CS=128, HALO=64, 2 channels/thread ----------------
__global__ void scan_kernel(const ushort_t* __restrict__ g, ushort_t* __restrict__ h) {
    int idx = blockIdx.x * 256 + threadIdx.x;
    int b = idx >> 9, d = (idx & 511) * 2;
    int chunk = blockIdx.y;
    const ushort_t* gb = g + (long)b * S_ * 1024 + d;
    ushort_t* hb = h + (long)b * S_ * 1024 + d;
    float h0 = 0.f, h1 = 0.f;
    int t0 = chunk * 128;
    int tw = t0 - 64; if (tw < 0) tw = 0;
#pragma unroll 4
    for (int t = tw; t < t0; ++t) {
        uint_t v = *(const uint_t*)(gb + (long)t * 1024);
        h0 = 0.9f * h0 + 0.1f * bf2f((ushort_t)(v & 0xffffu));
        h1 = 0.9f * h1 + 0.1f * bf2f((ushort_t)(v >> 16));
    }
#pragma unroll 4
    for (int t = t0; t < t0 + 128; ++t) {
        uint_t v = *(const uint_t*)(gb + (long)t * 1024);
        h0 = 0.9f * h0 + 0.1f * bf2f((ushort_t)(v & 0xffffu));
        h1 = 0.9f * h1 + 0.1f * bf2f((ushort_t)(v >> 16));
        *(uint_t*)(hb + (long)t * 1024) = (((uint_t)f2bf(h1)) << 16) | (uint_t)f2bf(h0);
    }
}

extern "C" void kernel_launch(void* const* d_in, const int* in_sizes, int n_in,
                              void* d_out, int out_size, void* d_ws, size_t ws_size,
                              hipStream_t stream) {
    const float* x     = (const float*)d_in[0];
    const float* W_in  = (const float*)d_in[1];
    const float* b_in  = (const float*)d_in[2];
    const float* W_out = (const float*)d_in[3];
    const float* b_out = (const float*)d_in[4];
    float* outp = (float*)d_out;

    char* ws = (char*)d_ws;
    ushort_t* xb   = (ushort_t*)ws;                        // 32 MB: x bf16, later reused for h bf16
    ushort_t* winT = (ushort_t*)(ws + 33554432);           // 4 MB
    ushort_t* woT  = (ushort_t*)(ws + 33554432 + 4194304); // 2 MB
    ushort_t* gbuf = (ushort_t*)(ws + 33554432 + 6291456); // 32 MB

    hipFuncSetAttribute((const void*)&gemm8_kernel<8, 1>, hipFuncAttributeMaxDynamicSharedMemorySize, 131072);
    hipFuncSetAttribute((const void*)&gemm8_kernel<4, 0>, hipFuncAttributeMaxDynamicSharedMemorySize, 131072);

    prep_kernel<<<11264, 256, 0, stream>>>((const float4*)x, xb, W_in, W_out, winT, woT);
    gemm8_kernel<8, 1><<<512, 512, 131072, stream>>>(xb, winT, b_in, (void*)gbuf);
    scan_kernel<<<dim3(8, 32), 256, 0, stream>>>(gbuf, xb);
    gemm8_kernel<4, 0><<<256, 512, 131072, stream>>>(xb, woT, b_out, (void*)outp);
}